// Round 8
// baseline (1039.193 us; speedup 1.0000x reference)
//
#include <hip/hip_runtime.h>
#include <math.h>

// SimplePlayerModel on MI355X — Round 8.
// R7 regression root-cause: demand-loaded global V frags in the MFMA stream
// (latency-exposed). R8: V^T staged via async global_load_lds double-buffer,
// chunk-major LDS layout (conflict-free b128 reads); K register-prefetch.
// Error-averaging analysis: P and V rounding errors average over the 512-token
// PV sum (dO ~ 6e-5) -> P-lo and V-lo planes dropped (PV MFMAs 3x fewer).
// GEMMs: col-split waves (64 rows x 64 cols/wave), W direct from L2-hot
// global with ring prefetch, ZERO barriers in K-loop (R6 was LDS-BW-bound:
// 4 waves redundantly reading all 256 cols).

typedef __bf16 bf16x8 __attribute__((ext_vector_type(8)));
typedef __bf16 bf16x4 __attribute__((ext_vector_type(4)));
typedef float  f32x4  __attribute__((ext_vector_type(4)));
typedef unsigned short u16;
typedef unsigned short u16x8 __attribute__((ext_vector_type(8)));

typedef __attribute__((address_space(1))) const unsigned char gas_char;
typedef __attribute__((address_space(3))) unsigned char las_char;
#define GLL16(g, l) __builtin_amdgcn_global_load_lds((gas_char*)(g), (las_char*)(l), 16, 0, 0)

__device__ __forceinline__ u16 f2b(float f) {            // fp32 -> bf16 RNE
    unsigned int u = __builtin_bit_cast(unsigned int, f);
    return (u16)((u + 0x7fffu + ((u >> 16) & 1u)) >> 16);
}
__device__ __forceinline__ float b2f(u16 u) {
    unsigned int v = ((unsigned int)u) << 16;
    return __builtin_bit_cast(float, v);
}
__device__ __forceinline__ bf16x8 ld2x64(const u16* p) {
    bf16x4 lo = *(const bf16x4*)p;
    bf16x4 hi = *(const bf16x4*)(p + 4);
    return __builtin_shufflevector(lo, hi, 0, 1, 2, 3, 4, 5, 6, 7);
}
__device__ __forceinline__ void split8(const float* __restrict__ s,
                                       bf16x8& hi, bf16x8& lo) {
    u16x8 h, l;
    #pragma unroll
    for (int j = 0; j < 8; ++j) {
        float v  = s[j];
        u16  hb  = f2b(v);
        h[j] = hb;
        l[j] = f2b(v - b2f(hb));
    }
    hi = __builtin_bit_cast(bf16x8, h);
    lo = __builtin_bit_cast(bf16x8, l);
}

// ------------------------------------------------ col-split bf16x3 GEMM core
// Block = 4 waves; wave wv computes 64 rows x cols [wv*64, wv*64+64).
// A rows rt*16+l16 (aofs = Abase + rowlocal*Astride); W cols colbase+nt*16+l16
// direct from global (L2-hot, all blocks share W). Ring-1 prefetch, no LDS,
// no barriers. acc[nt][rt].
template<int IN, bool AF32>
__device__ __forceinline__
void gemm8_core(const void* __restrict__ Xa, const void* __restrict__ Xb,
                long Abase, long Astride,
                const u16* __restrict__ Whi, const u16* __restrict__ Wlo,
                int colbase, int l16, int quad, f32x4 (&acc)[4][4])
{
    constexpr int KT = IN / 32;
    bf16x8 Ah[2][4], Al[2][4], Bh[2][4], Bl[2][4];
    auto loadK = [&](int kt, int sl) {
        #pragma unroll
        for (int rt = 0; rt < 4; ++rt) {
            long aofs = Abase + (rt * 16 + l16) * Astride + kt * 32 + quad * 8;
            if constexpr (AF32) {
                float av[8];
                *(f32x4*)&av[0] = *(const f32x4*)&((const float*)Xa)[aofs];
                *(f32x4*)&av[4] = *(const f32x4*)&((const float*)Xa)[aofs + 4];
                split8(av, Ah[sl][rt], Al[sl][rt]);
            } else {
                Ah[sl][rt] = *(const bf16x8*)&((const u16*)Xa)[aofs];
                Al[sl][rt] = *(const bf16x8*)&((const u16*)Xb)[aofs];
            }
        }
        #pragma unroll
        for (int nt = 0; nt < 4; ++nt) {
            long wofs = (long)(colbase + nt * 16 + l16) * IN + kt * 32 + quad * 8;
            Bh[sl][nt] = *(const bf16x8*)&Whi[wofs];
            Bl[sl][nt] = *(const bf16x8*)&Wlo[wofs];
        }
    };
    loadK(0, 0);
    if (KT > 1) loadK(1, 1);
    #pragma unroll
    for (int kt = 0; kt < KT; ++kt) {
        const int sl = kt & 1;
        #pragma unroll
        for (int nt = 0; nt < 4; ++nt)
            #pragma unroll
            for (int rt = 0; rt < 4; ++rt) {
                acc[nt][rt] = __builtin_amdgcn_mfma_f32_16x16x32_bf16(Al[sl][rt], Bh[sl][nt], acc[nt][rt], 0, 0, 0);
                acc[nt][rt] = __builtin_amdgcn_mfma_f32_16x16x32_bf16(Ah[sl][rt], Bl[sl][nt], acc[nt][rt], 0, 0, 0);
                acc[nt][rt] = __builtin_amdgcn_mfma_f32_16x16x32_bf16(Ah[sl][rt], Bh[sl][nt], acc[nt][rt], 0, 0, 0);
            }
        if (kt + 2 < KT) loadK(kt + 2, sl);
    }
}

// ---------------------------------------------- main linear (+bias+LN+res)
template<int IN, bool LN, bool RES, bool AF32, int OMODE>
__global__ __launch_bounds__(256, 2)
void gemm8_kernel(const void* __restrict__ Xa, const void* __restrict__ Xb, int ldX,
                  const u16* __restrict__ Whi, const u16* __restrict__ Wlo,
                  const float* __restrict__ bias,
                  const float* __restrict__ g, const float* __restrict__ beta,
                  const u16* __restrict__ resh, const u16* __restrict__ resl,
                  int ldRes, void* __restrict__ Y0, void* __restrict__ Y1, int ldY)
{
    __shared__ float r1[4][64], r2[4][64];
    const int tid = threadIdx.x;
    const int wv = tid >> 6, lane = tid & 63;
    const int quad = lane >> 4, l16 = lane & 15;
    const long rowblk = (long)blockIdx.x * 64;
    const int colbase = wv * 64;

    f32x4 acc[4][4];
    #pragma unroll
    for (int nt = 0; nt < 4; ++nt)
        #pragma unroll
        for (int rt = 0; rt < 4; ++rt) acc[nt][rt] = f32x4{0.f, 0.f, 0.f, 0.f};

    gemm8_core<IN, AF32>(Xa, Xb, rowblk * ldX, ldX, Whi, Wlo,
                         colbase, l16, quad, acc);

    // bias before LN stats
    #pragma unroll
    for (int nt = 0; nt < 4; ++nt) {
        float bc = bias[colbase + nt * 16 + l16];
        #pragma unroll
        for (int rt = 0; rt < 4; ++rt)
            #pragma unroll
            for (int r = 0; r < 4; ++r) acc[nt][rt][r] += bc;
    }

    float mean[4][4], rstd[4][4];   // [rt][r]
    if constexpr (LN) {
        float s1[4][4], s2[4][4];
        #pragma unroll
        for (int rt = 0; rt < 4; ++rt)
            #pragma unroll
            for (int r = 0; r < 4; ++r) { s1[rt][r] = 0.f; s2[rt][r] = 0.f; }
        #pragma unroll
        for (int nt = 0; nt < 4; ++nt)
            #pragma unroll
            for (int rt = 0; rt < 4; ++rt)
                #pragma unroll
                for (int r = 0; r < 4; ++r) {
                    s1[rt][r] += acc[nt][rt][r];
                    s2[rt][r] += acc[nt][rt][r] * acc[nt][rt][r];
                }
        #pragma unroll
        for (int off = 1; off < 16; off <<= 1)
            #pragma unroll
            for (int rt = 0; rt < 4; ++rt)
                #pragma unroll
                for (int r = 0; r < 4; ++r) {
                    s1[rt][r] += __shfl_xor(s1[rt][r], off, 64);
                    s2[rt][r] += __shfl_xor(s2[rt][r], off, 64);
                }
        if (l16 == 0) {
            #pragma unroll
            for (int rt = 0; rt < 4; ++rt)
                #pragma unroll
                for (int r = 0; r < 4; ++r) {
                    r1[wv][rt * 16 + quad * 4 + r] = s1[rt][r];
                    r2[wv][rt * 16 + quad * 4 + r] = s2[rt][r];
                }
        }
        __syncthreads();
        #pragma unroll
        for (int rt = 0; rt < 4; ++rt)
            #pragma unroll
            for (int r = 0; r < 4; ++r) {
                int row = rt * 16 + quad * 4 + r;
                float t1 = r1[0][row] + r1[1][row] + r1[2][row] + r1[3][row];
                float t2 = r2[0][row] + r2[1][row] + r2[2][row] + r2[3][row];
                mean[rt][r] = t1 * (1.0f / 256.f);
                float var = t2 * (1.0f / 256.f) - mean[rt][r] * mean[rt][r];
                rstd[rt][r] = rsqrtf(var + 1e-5f);
            }
    }

    #pragma unroll
    for (int nt = 0; nt < 4; ++nt) {
        int col = colbase + nt * 16 + l16;
        float gc = 1.f, bc2 = 0.f;
        if constexpr (LN) { gc = g[col]; bc2 = beta[col]; }
        #pragma unroll
        for (int rt = 0; rt < 4; ++rt)
            #pragma unroll
            for (int r = 0; r < 4; ++r) {
                long row = rowblk + rt * 16 + quad * 4 + r;
                float v = acc[nt][rt][r];
                if constexpr (LN) v = (v - mean[rt][r]) * rstd[rt][r] * gc + bc2;
                if constexpr (RES)
                    v += b2f(resh[row * ldRes + col]) + b2f(resl[row * ldRes + col]);
                long yofs = row * ldY + col;
                if constexpr (OMODE == 0) {
                    ((float*)Y0)[yofs] = v;
                } else if constexpr (OMODE == 1) {
                    u16 hb = f2b(v);
                    ((u16*)Y0)[yofs] = hb;
                    ((u16*)Y1)[yofs] = f2b(v - b2f(hb));
                } else {
                    ((u16*)Y0)[yofs] = f2b(v);
                }
            }
    }
}

// q,k projections (grid.y = wsel in {0,1}); bf16 token-major out; no barriers.
__global__ __launch_bounds__(256, 2)
void qkv8_proj(const u16* __restrict__ ph, const u16* __restrict__ pl,
               const u16* __restrict__ cwL, const float* __restrict__ cb,
               u16* __restrict__ qb, u16* __restrict__ kb)
{
    const int tid = threadIdx.x;
    const int wv = tid >> 6, lane = tid & 63;
    const int quad = lane >> 4, l16 = lane & 15;
    const int wsel = blockIdx.y;
    const u16* whi = cwL + (long)wsel * 65536;
    const u16* wlo = cwL + 393216 + (long)wsel * 65536;
    const float* bias = cb + wsel * 256;
    u16* Y = wsel ? kb : qb;
    const long rowblk = (long)blockIdx.x * 64;
    const int colbase = wv * 64;

    f32x4 acc[4][4];
    #pragma unroll
    for (int nt = 0; nt < 4; ++nt)
        #pragma unroll
        for (int rt = 0; rt < 4; ++rt) acc[nt][rt] = f32x4{0.f, 0.f, 0.f, 0.f};
    gemm8_core<256, false>(ph, pl, rowblk * 256, 256, whi, wlo,
                           colbase, l16, quad, acc);
    #pragma unroll
    for (int nt = 0; nt < 4; ++nt) {
        int col = colbase + nt * 16 + l16;
        float bc = bias[col];
        #pragma unroll
        for (int rt = 0; rt < 4; ++rt)
            #pragma unroll
            for (int r = 0; r < 4; ++r) {
                long row = rowblk + rt * 16 + quad * 4 + r;
                Y[row * 256 + col] = f2b(acc[nt][rt][r] + bc);
            }
    }
}

// v projection: s-major tiles + transposed store vt[n][d][s] (hi only).
// Block b: n = b&63, sblk = b>>6; token(rowlocal) = (sblk*64+rowlocal)*64+n.
__global__ __launch_bounds__(256, 2)
void v8_proj(const u16* __restrict__ ph, const u16* __restrict__ pl,
             const u16* __restrict__ whi, const u16* __restrict__ wlo,
             const float* __restrict__ bias, u16* __restrict__ vth)
{
    const int tid = threadIdx.x;
    const int wv = tid >> 6, lane = tid & 63;
    const int quad = lane >> 4, l16 = lane & 15;
    const int n = blockIdx.x & 63, sblk = blockIdx.x >> 6;
    const int colbase = wv * 64;
    const long Abase = ((long)sblk * 64 * 64 + n) * 256;   // + rowlocal*64*256

    f32x4 acc[4][4];
    #pragma unroll
    for (int nt = 0; nt < 4; ++nt)
        #pragma unroll
        for (int rt = 0; rt < 4; ++rt) acc[nt][rt] = f32x4{0.f, 0.f, 0.f, 0.f};
    gemm8_core<256, false>(ph, pl, Abase, 64 * 256, whi, wlo,
                           colbase, l16, quad, acc);

    #pragma unroll
    for (int nt = 0; nt < 4; ++nt) {
        int d = colbase + nt * 16 + l16;
        float bc = bias[d];
        #pragma unroll
        for (int rt = 0; rt < 4; ++rt) {
            ushort4 hv;
            #pragma unroll
            for (int r = 0; r < 4; ++r)
                ((u16*)&hv)[r] = f2b(acc[nt][rt][r] + bc);
            long ofs = ((long)n * 256 + d) * 512 + sblk * 64 + rt * 16 + quad * 4;
            *(ushort4*)&vth[ofs] = hv;
        }
    }
}

// ----------------------------------------------- combined in_proj @ qkv_proj
__global__ __launch_bounds__(256)
void combine_kernel(const float* __restrict__ inw, const float* __restrict__ inb,
                    const float* __restrict__ qw, const float* __restrict__ kw,
                    const float* __restrict__ vw, const float* __restrict__ qb,
                    const float* __restrict__ kb, const float* __restrict__ vb,
                    u16* __restrict__ cw, float* __restrict__ cb)
{
    int idx = blockIdx.y, L = idx / 3, wsel = idx % 3;
    const float* Wa = inw + (long)L * 768 * 256 + wsel * 65536;
    const float* ba = inb + L * 768 + wsel * 256;
    const float* Wf = (wsel == 0 ? qw : wsel == 1 ? kw : vw) + (long)L * 65536;
    const float* bf = (wsel == 0 ? qb : wsel == 1 ? kb : vb) + L * 256;

    int o = blockIdx.x, j = threadIdx.x;
    float s = 0.f;
    for (int mm = 0; mm < 256; ++mm)
        s += Wa[o * 256 + mm] * Wf[mm * 256 + j];
    u16 hb = f2b(s);
    cw[(long)idx * 65536 + o * 256 + j] = hb;
    cw[393216 + (long)idx * 65536 + o * 256 + j] = f2b(s - b2f(hb));

    __shared__ float red[256];
    red[j] = Wa[o * 256 + j] * bf[j];
    __syncthreads();
    for (int st = 128; st > 0; st >>= 1) {
        if (j < st) red[j] += red[j + st];
        __syncthreads();
    }
    if (j == 0) cb[idx * 256 + o] = red[0] + ba[o];
}

// ------------------------------------------- fp32 -> hi/lo bf16 weight planes
__global__ __launch_bounds__(256)
void cast_split_multi(const float* s0, u16* d0, int n0,
                      const float* s1, u16* d1, int n1,
                      const float* s2, u16* d2, int n2,
                      const float* s3, u16* d3, int n3,
                      const float* s4, u16* d4, int n4,
                      const float* s5, u16* d5, int n5)
{
    const float* s; u16* d; int n;
    switch (blockIdx.y) {
        case 0: s = s0; d = d0; n = n0; break;
        case 1: s = s1; d = d1; n = n1; break;
        case 2: s = s2; d = d2; n = n2; break;
        case 3: s = s3; d = d3; n = n3; break;
        case 4: s = s4; d = d4; n = n4; break;
        default: s = s5; d = d5; n = n5; break;
    }
    int i = (blockIdx.x * 256 + threadIdx.x) * 4;
    if (i >= n) return;
    float4 v = *(const float4*)&s[i];
    ushort4 h, l;
    h.x = f2b(v.x); l.x = f2b(v.x - b2f(h.x));
    h.y = f2b(v.y); l.y = f2b(v.y - b2f(h.y));
    h.z = f2b(v.z); l.z = f2b(v.z - b2f(h.z));
    h.w = f2b(v.w); l.w = f2b(v.w - b2f(h.w));
    *(ushort4*)&d[i] = h;
    *(ushort4*)&d[n + i] = l;
}

// ------------------------------------------------------- MFMA flash attention
// grid (n=64, h=4, sq=4). V^T tiles staged via async global_load_lds into
// chunk-major LDS (slot = q*64 + d -> quarter-wave-contiguous b128 reads,
// conflict-free), double-buffered (1 barrier/tb). K register-prefetched one
// tb ahead. P hi-only (errors average over 512-token PV sum).
#define PS  68
#define EXP2SCALE 0.18033688089184986f   // 0.125 * log2(e)

__global__ __launch_bounds__(256, 2)
void attn8_kernel(const u16* __restrict__ qbuf, const u16* __restrict__ kbuf,
                  const u16* __restrict__ vth,
                  u16* __restrict__ ofh, u16* __restrict__ ofl)
{
    const int n = blockIdx.x, h = blockIdx.y, sq = blockIdx.z;
    const int tid = threadIdx.x;
    const int wv = tid >> 6, lane = tid & 63;
    const int quad = lane >> 4, l16 = lane & 15;

    __shared__ u16 VB[2][4096];          // [buf][chunk q*64+d][8]
    __shared__ u16 Pbh[4][32 * PS];

    const long vbase = ((long)n * 256 + h * 64) * 512;
    // staging: 512 chunks of 16B; thread stages cid = tid, tid+256
    const int sd = tid & 63, scp = tid >> 6;     // d, chunkpos base
    auto stageV = [&](int tb, int buf) {
        #pragma unroll
        for (int i = 0; i < 2; ++i) {
            int cid = tid + i * 256;
            GLL16(vth + vbase + (long)sd * 512 + tb * 64 + (scp + i * 4) * 8,
                  (unsigned char*)&VB[0][0] + buf * 8192 + cid * 16);
        }
    };
    bf16x8 kfr[2][8];
    auto loadK = [&](int tb, int sl) {
        #pragma unroll
        for (int kc = 0; kc < 2; ++kc)
            #pragma unroll
            for (int tt = 0; tt < 4; ++tt)
                kfr[sl][kc * 4 + tt] = *(const bf16x8*)
                    &kbuf[((long)(tb * 64 + tt * 16 + l16) * 64 + n) * 256
                          + h * 64 + kc * 32 + quad * 8];
    };

    bf16x8 qf[2][2];
    #pragma unroll
    for (int rt = 0; rt < 2; ++rt)
        #pragma unroll
        for (int kc = 0; kc < 2; ++kc) {
            long s = sq * 128 + wv * 32 + rt * 16 + l16;
            qf[rt][kc] = *(const bf16x8*)&qbuf[(s * 64 + n) * 256 + h * 64
                                               + kc * 32 + quad * 8];
        }

    f32x4 o[2][4];
    #pragma unroll
    for (int rt = 0; rt < 2; ++rt)
        #pragma unroll
        for (int dt = 0; dt < 4; ++dt) o[rt][dt] = f32x4{0.f, 0.f, 0.f, 0.f};
    float l_run[2][4] = {{0.f, 0.f, 0.f, 0.f}, {0.f, 0.f, 0.f, 0.f}};

    stageV(0, 0);
    loadK(0, 0);
    __syncthreads();

    for (int tb = 0; tb < 8; ++tb) {
        const int buf = tb & 1;
        if (tb < 7) { stageV(tb + 1, buf ^ 1); loadK(tb + 1, buf ^ 1); }

        // ---- scores S = Q K^T
        f32x4 sA[2][4];
        #pragma unroll
        for (int rt = 0; rt < 2; ++rt)
            #pragma unroll
            for (int tt = 0; tt < 4; ++tt) sA[rt][tt] = f32x4{0.f, 0.f, 0.f, 0.f};
        #pragma unroll
        for (int kc = 0; kc < 2; ++kc)
            #pragma unroll
            for (int tt = 0; tt < 4; ++tt) {
                bf16x8 kf = kfr[buf][kc * 4 + tt];
                sA[0][tt] = __builtin_amdgcn_mfma_f32_16x16x32_bf16(
                    qf[0][kc], kf, sA[0][tt], 0, 0, 0);
                sA[1][tt] = __builtin_amdgcn_mfma_f32_16x16x32_bf16(
                    qf[1][kc], kf, sA[1][tt], 0, 0, 0);
            }

        // ---- softmax numerators (no max shift; scores O(0.1))
        #pragma unroll
        for (int rt = 0; rt < 2; ++rt)
            #pragma unroll
            for (int r = 0; r < 4; ++r) {
                float p0 = exp2f(sA[rt][0][r] * EXP2SCALE);
                float p1 = exp2f(sA[rt][1][r] * EXP2SCALE);
                float p2 = exp2f(sA[rt][2][r] * EXP2SCALE);
                float p3 = exp2f(sA[rt][3][r] * EXP2SCALE);
                int prow = (rt * 16 + quad * 4 + r) * PS + l16;
                Pbh[wv][prow +  0] = f2b(p0);
                Pbh[wv][prow + 16] = f2b(p1);
                Pbh[wv][prow + 32] = f2b(p2);
                Pbh[wv][prow + 48] = f2b(p3);
                l_run[rt][r] += (p0 + p1) + (p2 + p3);
            }

        // ---- O += P V (P hi, V hi from chunk-major LDS)
        #pragma unroll
        for (int kc = 0; kc < 2; ++kc) {
            bf16x8 pfh[2];
            #pragma unroll
            for (int rt = 0; rt < 2; ++rt)
                pfh[rt] = ld2x64(&Pbh[wv][(rt * 16 + l16) * PS
                                          + kc * 32 + quad * 8]);
            #pragma unroll
            for (int dt = 0; dt < 4; ++dt) {
                bf16x8 vfh = *(const bf16x8*)
                    &VB[buf][((kc * 4 + quad) * 64 + dt * 16 + l16) * 8];
                o[0][dt] = __builtin_amdgcn_mfma_f32_16x16x32_bf16(
                    pfh[0], vfh, o[0][dt], 0, 0, 0);
                o[1][dt] = __builtin_amdgcn_mfma_f32_16x16x32_bf16(
                    pfh[1], vfh, o[1][dt], 0, 0, 0);
            }
        }
        if (tb < 7) __syncthreads();
    }

    // final l reduce across the 16 t-lanes
    #pragma unroll
    for (int off = 1; off < 16; off <<= 1)
        #pragma unroll
        for (int rt = 0; rt < 2; ++rt)
            #pragma unroll
            for (int r = 0; r < 4; ++r)
                l_run[rt][r] += __shfl_xor(l_run[rt][r], off, 64);

    #pragma unroll
    for (int rt = 0; rt < 2; ++rt)
        #pragma unroll
        for (int r = 0; r < 4; ++r) {
            float inv = 1.0f / l_run[rt][r];
            long s = sq * 128 + wv * 32 + rt * 16 + quad * 4 + r;
            #pragma unroll
            for (int dt = 0; dt < 4; ++dt) {
                long idx = (s * 64 + n) * 256 + h * 64 + dt * 16 + l16;
                float val = o[rt][dt][r] * inv;
                u16 hb = f2b(val);
                ofh[idx] = hb;
                ofl[idx] = f2b(val - b2f(hb));
            }
        }
}

// -------------------------------------------------- masked team segment-sum
__global__ __launch_bounds__(256)
void team_reduce_kernel(const float* __restrict__ x, const u16* __restrict__ ph,
                        const u16* __restrict__ pl, float* __restrict__ teams)
{
    int b = blockIdx.x, d = threadIdx.x;
    float acc = 0.f;
    for (int pp = 0; pp < 64; ++pp) {
        float flag = x[((long)b * 64 + pp) * 64 + 63];
        if (flag == 1.0f) {
            long idx = ((long)b * 64 + pp) * 256 + d;
            acc += b2f(ph[idx]) + b2f(pl[idx]);
        }
    }
    teams[(long)b * 512 + d]       = acc;
    teams[(long)b * 512 + 256 + d] = acc;
}

// ---------------------------------------- tail GEMM (512-row team layers)
template<int IN, int OUT, bool RES>
__global__ __launch_bounds__(256)
void tail_gemm(const float* __restrict__ X,
               const u16* __restrict__ Whi, const u16* __restrict__ Wlo,
               const float* __restrict__ bias,
               const float* __restrict__ g, const float* __restrict__ beta,
               const float* __restrict__ res, float* __restrict__ Y)
{
    constexpr int NTW = OUT / 64;
    constexpr int KT  = IN / 32;
    const int tid = threadIdx.x;
    const int wv = tid >> 6, lane = tid & 63;
    const int quad = lane >> 4, l16 = lane & 15;
    const int row0 = blockIdx.x * 16;
    const int colbase = wv * (OUT / 4);

    f32x4 acc[NTW];
    #pragma unroll
    for (int nt = 0; nt < NTW; ++nt) acc[nt] = f32x4{0.f, 0.f, 0.f, 0.f};

    #pragma unroll
    for (int kt = 0; kt < KT; ++kt) {
        float av[8];
        long aofs = (long)(row0 + l16) * IN + kt * 32 + quad * 8;
        *(f32x4*)&av[0] = *(const f32x4*)&X[aofs];
        *(f32x4*)&av[4] = *(const f32x4*)&X[aofs + 4];
        bf16x8 ah, al;
        split8(av, ah, al);
        #pragma unroll
        for (int nt = 0; nt < NTW; ++nt) {
            long wofs = (long)(colbase + nt * 16 + l16) * IN + kt * 32 + quad * 8;
            bf16x8 bhi = *(const bf16x8*)&Whi[wofs];
            bf16x8 blo = *(const bf16x8*)&Wlo[wofs];
            acc[nt] = __builtin_amdgcn_mfma_f32_16x16x32_bf16(al, bhi, acc[nt], 0, 0, 0);
            acc[nt] = __builtin_amdgcn_mfma_f32_16x16x32_bf16(ah, blo, acc[nt], 0, 0, 0);
            acc[nt] = __builtin_amdgcn_mfma_f32_16x16x32_bf16(ah, bhi, acc[nt], 0, 0, 0);
        }
    }

    #pragma unroll
    for (int nt = 0; nt < NTW; ++nt) {
        float bc = bias[colbase + nt * 16 + l16];
        #pragma unroll
        for (int r = 0; r < 4; ++r) acc[nt][r] += bc;
    }

    float s1[4] = {0, 0, 0, 0}, s2[4] = {0, 0, 0, 0};
    #pragma unroll
    for (int nt = 0; nt < NTW; ++nt)
        #pragma unroll
        for (int r = 0; r < 4; ++r) {
            s1[r] += acc[nt][r];
            s2[r] += acc[nt][r] * acc[nt][r];
        }
    #pragma unroll
    for (int off = 1; off < 16; off <<= 1)
        #pragma unroll
        for (int r = 0; r < 4; ++r) {
            s1[r] += __shfl_xor(s1[r], off, 64);
            s2[r] += __shfl_xor(s2[r], off, 64);
        }
    __shared__ float r1[64], r2[64];
    if (l16 == 0) {
        #pragma unroll
        for (int r = 0; r < 4; ++r) {
            r1[wv * 16 + quad * 4 + r] = s1[r];
            r2[wv * 16 + quad * 4 + r] = s2[r];
        }
    }
    __syncthreads();
    float mean[4], rstd[4];
    #pragma unroll
    for (int r = 0; r < 4; ++r) {
        int rr = quad * 4 + r;
        float t1 = r1[rr] + r1[16 + rr] + r1[32 + rr] + r1[48 + rr];
        float t2 = r2[rr] + r2[16 + rr] + r2[32 + rr] + r2[48 + rr];
        mean[r] = t1 * (1.0f / OUT);
        float var = t2 * (1.0f / OUT) - mean[r] * mean[r];
        rstd[r] = rsqrtf(var + 1e-5f);
    }
    #pragma unroll
    for (int nt = 0; nt < NTW; ++nt) {
        int col = colbase + nt * 16 + l16;
        float gc = g[col], bc2 = beta[col];
        #pragma unroll
        for (int r = 0; r < 4; ++r) {
            int row = row0 + quad * 4 + r;
            float v = (acc[nt][r] - mean[r]) * rstd[r] * gc + bc2;
            if constexpr (RES) v += res[(long)row * OUT + col];
            Y[(long)row * OUT + col] = v;
        }
    }
}

// -------------------------------------------------------- standalone LN (lnf)
__global__ __launch_bounds__(64)
void ln_kernel(const float* __restrict__ X, const float* __restrict__ g,
               const float* __restrict__ b, float* __restrict__ Y)
{
    int row = blockIdx.x, lane = threadIdx.x;
    float4 v = *(const float4*)&X[(long)row * 256 + lane * 4];
    float s1 = v.x + v.y + v.z + v.w;
    float s2 = v.x*v.x + v.y*v.y + v.z*v.z + v.w*v.w;
    #pragma unroll
    for (int off = 32; off > 0; off >>= 1) {
        s1 += __shfl_xor(s1, off, 64);
        s2 += __shfl_xor(s2, off, 64);
    }
    float mean = s1 * (1.f / 256.f);
    float rstd = rsqrtf(s2 * (1.f / 256.f) - mean * mean + 1e-5f);
    float4 gg = *(const float4*)&g[lane * 4];
    float4 bb = *(const float4*)&b[lane * 4];
    float4 o;
    o.x = (v.x - mean) * rstd * gg.x + bb.x;
    o.y = (v.y - mean) * rstd * gg.y + bb.y;
    o.z = (v.z - mean) * rstd * gg.z + bb.z;
    o.w = (v.w - mean) * rstd * gg.w + bb.w;
    *(float4*)&Y[(long)row * 256 + lane * 4] = o;
}

// ------------------------------------------------------------- final predict
__global__ __launch_bounds__(64)
void pred_kernel(const float* __restrict__ X, const float* __restrict__ pw,
                 const float* __restrict__ pb, float* __restrict__ out)
{
    int row = blockIdx.x, lane = threadIdx.x;
    float4 v = *(const float4*)&X[(long)row * 256 + lane * 4];
    float4 w = *(const float4*)&pw[lane * 4];
    float s = v.x*w.x + v.y*w.y + v.z*w.z + v.w*w.w;
    #pragma unroll
    for (int off = 32; off > 0; off >>= 1) s += __shfl_xor(s, off, 64);
    if (lane == 0) out[row] = s + pb[0];
}

// =========================================================================
extern "C" void kernel_launch(void* const* d_in, const int* in_sizes, int n_in,
                              void* d_out, int out_size, void* d_ws, size_t ws_size,
                              hipStream_t stream)
{
    const float* x         = (const float*)d_in[0];
    const float* emb_w     = (const float*)d_in[1];
    const float* emb_b     = (const float*)d_in[2];
    const float* emb_g     = (const float*)d_in[3];
    const float* emb_beta  = (const float*)d_in[4];
    const float* post_w    = (const float*)d_in[5];
    const float* post_b    = (const float*)d_in[6];
    const float* post_g    = (const float*)d_in[7];
    const float* post_beta = (const float*)d_in[8];
    const float* attn_qw   = (const float*)d_in[9];
    const float* attn_qb   = (const float*)d_in[10];
    const float* attn_kw   = (const float*)d_in[11];
    const float* attn_kb   = (const float*)d_in[12];
    const float* attn_vw   = (const float*)d_in[13];
    const float* attn_vb   = (const float*)d_in[14];
    const float* attn_inw  = (const float*)d_in[15];
    const float* attn_inb  = (const float*)d_in[16];
    const float* attn_outw = (const float*)d_in[17];
    const float* attn_outb = (const float*)d_in[18];
    const float* attn_g    = (const float*)d_in[19];
    const float* attn_beta = (const float*)d_in[20];
    const float* player_w  = (const float*)d_in[21];
    const float* player_b  = (const float*)d_in[22];
    const float* player_g  = (const float*)d_in[23];
    const float* player_bt = (const float*)d_in[24];
    const float* team_w    = (const float*)d_in[25];
    const float* team_b    = (const float*)d_in[26];
    const float* team_g    = (const float*)d_in[27];
    const float* team_beta = (const float*)d_in[28];
    const float* pre_w     = (const float*)d_in[29];
    const float* pre_b     = (const float*)d_in[30];
    const float* pre_g     = (const float*)d_in[31];
    const float* pre_beta  = (const float*)d_in[32];
    const float* lnf_g     = (const float*)d_in[33];
    const float* lnf_b     = (const float*)d_in[34];
    const float* pred_w    = (const float*)d_in[35];
    const float* pred_b    = (const float*)d_in[36];

    // ---- workspace layout
    char* base = (char*)d_ws;
    const size_t NR = (size_t)32768 * 256;
    u16* ph  = (u16*)base;  base += NR * 2;
    u16* pl  = (u16*)base;  base += NR * 2;
    u16* ofh = (u16*)base;  base += NR * 2;
    u16* ofl = (u16*)base;  base += NR * 2;
    u16* vth = (u16*)base;  base += NR * 2;     // V^T [n][d(256)][s(512)]
    u16* qb  = (u16*)base;  base += NR * 2;
    u16* kb  = (u16*)base;  base += NR * 2;
    float* teams0 = (float*)base; base += (size_t)512 * 512 * 4;
    float* teams1 = (float*)base; base += (size_t)512 * 512 * 4;
    float* o5     = (float*)base; base += (size_t)512 * 256 * 4;
    u16* emb_wp    = (u16*)base;  base += (size_t)2 * 16384 * 2;
    u16* post_wp   = (u16*)base;  base += (size_t)2 * 65536 * 2;
    u16* outw_p    = (u16*)base;  base += (size_t)2 * 131072 * 2;
    u16* player_wp = (u16*)base;  base += (size_t)2 * 131072 * 2;
    u16* team_wp   = (u16*)base;  base += (size_t)2 * 524288 * 2;
    u16* pre_wp    = (u16*)base;  base += (size_t)2 * 131072 * 2;
    u16* cwb       = (u16*)base;  base += (size_t)2 * 393216 * 2;
    float* cbf     = (float*)base; base += (size_t)1536 * 4;

    // 1) weights -> hi/lo bf16 planes
    cast_split_multi<<<dim3(512, 6), 256, 0, stream>>>(
        emb_w, emb_wp, 16384,
        post_w, post_wp, 65536,
        attn_outw, outw_p, 131072,
        player_w, player_wp, 131072,
        team_w, team_wp, 524288,
        pre_w, pre_wp, 131072);

    // 2) combined qkv weights
    combine_kernel<<<dim3(256, 6), 256, 0, stream>>>(
        attn_inw, attn_inb, attn_qw, attn_kw, attn_vw,
        attn_qb, attn_kb, attn_vb, cwb, cbf);

    // 3) embedding + post-embedding
    gemm8_kernel<64, true, false, true, 1><<<512, 256, 0, stream>>>(
        x, nullptr, 64, emb_wp, emb_wp + 16384, emb_b, emb_g, emb_beta,
        nullptr, nullptr, 0, ph, pl, 256);
    gemm8_kernel<256, true, true, false, 1><<<512, 256, 0, stream>>>(
        ph, pl, 256, post_wp, post_wp + 65536, post_b, post_g, post_beta,
        ph, pl, 256, ph, pl, 256);

    // 4) attention layers
    for (int L = 0; L < 2; ++L) {
        const u16* cwL = cwb + (size_t)L * 3 * 65536;
        qkv8_proj<<<dim3(512, 2), 256, 0, stream>>>(
            ph, pl, cwL, cbf + L * 768, qb, kb);
        v8_proj<<<512, 256, 0, stream>>>(
            ph, pl, cwL + 2 * 65536, cwL + 393216 + 2 * 65536,
            cbf + L * 768 + 512, vth);
        attn8_kernel<<<dim3(64, 4, 4), 256, 0, stream>>>(
            qb, kb, vth, ofh, ofl);
        gemm8_kernel<256, true, true, false, 1><<<512, 256, 0, stream>>>(
            ofh, ofl, 256, outw_p + (size_t)L * 65536,
            outw_p + 131072 + (size_t)L * 65536, attn_outb + L * 256,
            attn_g + L * 256, attn_beta + L * 256, ph, pl, 256, ph, pl, 256);
    }

    // 5) player layers
    for (int L = 0; L < 2; ++L)
        gemm8_kernel<256, true, true, false, 1><<<512, 256, 0, stream>>>(
            ph, pl, 256, player_wp + (size_t)L * 65536,
            player_wp + 131072 + (size_t)L * 65536, player_b + L * 256,
            player_g + L * 256, player_bt + L * 256, ph, pl, 256, ph, pl, 256);

    // 6) masked segment-sum -> teams0 fp32 [512][512]
    team_reduce_kernel<<<512, 256, 0, stream>>>(x, ph, pl, teams0);

    // 7) team layers (ping-pong)
    tail_gemm<512, 512, true><<<32, 256, 0, stream>>>(
        teams0, team_wp, team_wp + 524288, team_b,
        team_g, team_beta, teams0, teams1);
    tail_gemm<512, 512, true><<<32, 256, 0, stream>>>(
        teams1, team_wp + 262144, team_wp + 524288 + 262144, team_b + 512,
        team_g + 512, team_beta + 512, teams1, teams0);

    // 8) pre (512->256) + lnf + pred
    tail_gemm<512, 256, false><<<32, 256, 0, stream>>>(
        teams0, pre_wp, pre_wp + 131072, pre_b, pre_g, pre_beta,
        nullptr, o5);
    ln_kernel<<<512, 64, 0, stream>>>(o5, lnf_g, lnf_b, o5);
    pred_kernel<<<512, 64, 0, stream>>>(o5, pred_w, pred_b, (float*)d_out);
}

// Round 9
// 772.972 us; speedup vs baseline: 1.3444x; 1.3444x over previous
//
#include <hip/hip_runtime.h>
#include <math.h>

// SimplePlayerModel on MI355X — Round 9.
// R8 post-mortem: global V^T producer/consumer path made attn HBM-bound
// (scattered 8B stores + 1KB-stride GLL16 reads across non-coherent L2s,
// 470 MB HBM/dispatch); no-LDS col-split GEMM exposed W L2 latency. Both
// reverted to the R6 structure (best: 799us). Kept from R8 (empirically
// validated, absmax unchanged): P and V single-plane bf16 in attention —
// PV MFMAs 3x fewer, V staging + transpose halved, attn LDS 51.7->25.9 KB.

typedef __bf16 bf16x8 __attribute__((ext_vector_type(8)));
typedef __bf16 bf16x4 __attribute__((ext_vector_type(4)));
typedef __bf16 bf16x2 __attribute__((ext_vector_type(2)));
typedef float  f32x4  __attribute__((ext_vector_type(4)));
typedef unsigned short u16;
typedef unsigned short u16x8 __attribute__((ext_vector_type(8)));

__device__ __forceinline__ u16 f2b(float f) {            // fp32 -> bf16 RNE
    unsigned int u = __builtin_bit_cast(unsigned int, f);
    return (u16)((u + 0x7fffu + ((u >> 16) & 1u)) >> 16);
}
__device__ __forceinline__ float b2f(u16 u) {
    unsigned int v = ((unsigned int)u) << 16;
    return __builtin_bit_cast(float, v);
}
__device__ __forceinline__ bf16x8 ld2x64(const u16* p) { // two 8B LDS loads
    bf16x4 lo = *(const bf16x4*)p;
    bf16x4 hi = *(const bf16x4*)(p + 4);
    return __builtin_shufflevector(lo, hi, 0, 1, 2, 3, 4, 5, 6, 7);
}
__device__ __forceinline__ bf16x8 ld4x32(const u16* p) { // four 4B LDS loads
    bf16x2 a = *(const bf16x2*)p,     b = *(const bf16x2*)(p + 2);
    bf16x2 c = *(const bf16x2*)(p + 4), d = *(const bf16x2*)(p + 6);
    bf16x4 lo = __builtin_shufflevector(a, b, 0, 1, 2, 3);
    bf16x4 hi = __builtin_shufflevector(c, d, 0, 1, 2, 3);
    return __builtin_shufflevector(lo, hi, 0, 1, 2, 3, 4, 5, 6, 7);
}
__device__ __forceinline__ void split8(const float* __restrict__ s,
                                       bf16x8& hi, bf16x8& lo) {
    u16x8 h, l;
    #pragma unroll
    for (int j = 0; j < 8; ++j) {
        float v  = s[j];
        u16  hb  = f2b(v);
        h[j] = hb;
        l[j] = f2b(v - b2f(hb));
    }
    hi = __builtin_bit_cast(bf16x8, h);
    lo = __builtin_bit_cast(bf16x8, l);
}

// --------------------------------------------- LDS-staged bf16x3 MFMA GEMM
// Block = 256 thr, 64 rows (4 waves x 16 rows), OUT=256 cols. W (hi+lo)
// double-buffered in LDS (2 x 32KB), one barrier/kt. A prefetched 2 kt ahead.
template<int IN, bool LN, bool RES, bool AF32, int OMODE>
__device__ __forceinline__
void gemm_body(const void* __restrict__ Xa, const void* __restrict__ Xb, int ldX,
               const u16* __restrict__ Whi, const u16* __restrict__ Wlo,
               const float* __restrict__ bias,
               const float* __restrict__ g, const float* __restrict__ beta,
               const u16* __restrict__ resh, const u16* __restrict__ resl,
               int ldRes, void* __restrict__ Y0, void* __restrict__ Y1, int ldY,
               u16* __restrict__ Wb)
{
    constexpr int KT = IN / 32;
    const int tid = threadIdx.x;
    const int wv = tid >> 6, lane = tid & 63;
    const int quad = lane >> 4, l16 = lane & 15;
    const long arow = (long)blockIdx.x * 64 + wv * 16 + l16;

    const u16* sbase[8];
    int sdst[8];
    #pragma unroll
    for (int i = 0; i < 8; ++i) {
        int cid = tid + i * 256;
        int plane = cid >> 10, nt = (cid >> 6) & 15, slot = cid & 63;
        int q = slot >> 4, c = slot & 15;
        sbase[i] = (plane ? Wlo : Whi) + (long)(nt * 16 + c) * IN + q * 8;
        sdst[i]  = (plane * 16 + nt) * 512 + slot * 8;
    }
    u16x8 wreg[8];
    auto issueW = [&](int kt) {
        #pragma unroll
        for (int i = 0; i < 8; ++i) wreg[i] = *(const u16x8*)(sbase[i] + kt * 32);
    };
    auto commitW = [&](int buf) {
        #pragma unroll
        for (int i = 0; i < 8; ++i)
            *(u16x8*)&Wb[buf * 16384 + sdst[i]] = wreg[i];
    };

    bf16x8 ah[3], al[3];
    auto loadA = [&](int kt) {
        int s = kt % 3;
        long aofs = arow * (long)ldX + kt * 32 + quad * 8;
        if constexpr (AF32) {
            float av[8];
            *(f32x4*)&av[0] = *(const f32x4*)&((const float*)Xa)[aofs];
            *(f32x4*)&av[4] = *(const f32x4*)&((const float*)Xa)[aofs + 4];
            split8(av, ah[s], al[s]);
        } else {
            ah[s] = *(const bf16x8*)&((const u16*)Xa)[aofs];
            al[s] = *(const bf16x8*)&((const u16*)Xb)[aofs];
        }
    };

    f32x4 acc[16];
    #pragma unroll
    for (int nt = 0; nt < 16; ++nt) acc[nt] = f32x4{0.f, 0.f, 0.f, 0.f};

    issueW(0);
    commitW(0);
    if (KT > 1) issueW(1);
    loadA(0);
    if (KT > 1) loadA(1);
    __syncthreads();

    #pragma unroll
    for (int kt = 0; kt < KT; ++kt) {
        if (kt + 2 < KT) loadA(kt + 2);
        const u16* wb = Wb + (kt & 1) * 16384;
        const int s = kt % 3;
        #pragma unroll
        for (int nt = 0; nt < 16; ++nt) {
            bf16x8 bhi = *(const bf16x8*)&wb[nt * 512 + lane * 8];
            bf16x8 blo = *(const bf16x8*)&wb[(16 + nt) * 512 + lane * 8];
            acc[nt] = __builtin_amdgcn_mfma_f32_16x16x32_bf16(al[s], bhi, acc[nt], 0, 0, 0);
            acc[nt] = __builtin_amdgcn_mfma_f32_16x16x32_bf16(ah[s], blo, acc[nt], 0, 0, 0);
            acc[nt] = __builtin_amdgcn_mfma_f32_16x16x32_bf16(ah[s], bhi, acc[nt], 0, 0, 0);
        }
        if (kt + 1 < KT) {
            commitW((kt + 1) & 1);
            if (kt + 2 < KT) issueW(kt + 2);
            __syncthreads();
        }
    }

    #pragma unroll
    for (int nt = 0; nt < 16; ++nt) {
        float bc = bias[nt * 16 + l16];
        #pragma unroll
        for (int r = 0; r < 4; ++r) acc[nt][r] += bc;
    }

    float mean[4], rstd[4];
    if constexpr (LN) {
        float s1[4] = {0, 0, 0, 0}, s2[4] = {0, 0, 0, 0};
        #pragma unroll
        for (int nt = 0; nt < 16; ++nt)
            #pragma unroll
            for (int r = 0; r < 4; ++r) {
                s1[r] += acc[nt][r];
                s2[r] += acc[nt][r] * acc[nt][r];
            }
        #pragma unroll
        for (int off = 1; off < 16; off <<= 1)
            #pragma unroll
            for (int r = 0; r < 4; ++r) {
                s1[r] += __shfl_xor(s1[r], off, 64);
                s2[r] += __shfl_xor(s2[r], off, 64);
            }
        #pragma unroll
        for (int r = 0; r < 4; ++r) {
            mean[r] = s1[r] * (1.0f / 256.f);
            float var = s2[r] * (1.0f / 256.f) - mean[r] * mean[r];
            rstd[r] = rsqrtf(var + 1e-5f);
        }
    }
    #pragma unroll
    for (int nt = 0; nt < 16; ++nt) {
        int col = nt * 16 + l16;
        float gc = 1.f, bc2 = 0.f;
        if constexpr (LN) { gc = g[col]; bc2 = beta[col]; }
        #pragma unroll
        for (int r = 0; r < 4; ++r) {
            long row = (long)blockIdx.x * 64 + wv * 16 + quad * 4 + r;
            float v = acc[nt][r];
            if constexpr (LN) v = (v - mean[r]) * rstd[r] * gc + bc2;
            if constexpr (RES)
                v += b2f(resh[row * ldRes + col]) + b2f(resl[row * ldRes + col]);
            long yofs = row * ldY + col;
            if constexpr (OMODE == 0) {
                ((float*)Y0)[yofs] = v;
            } else if constexpr (OMODE == 1) {
                u16 hb = f2b(v);
                ((u16*)Y0)[yofs] = hb;
                ((u16*)Y1)[yofs] = f2b(v - b2f(hb));
            } else {
                ((u16*)Y0)[yofs] = f2b(v);
            }
        }
    }
}

template<int IN, bool LN, bool RES, bool AF32, int OMODE>
__global__ __launch_bounds__(256)
void gemm_kernel(const void* __restrict__ Xa, const void* __restrict__ Xb, int ldX,
                 const u16* __restrict__ Whi, const u16* __restrict__ Wlo,
                 const float* __restrict__ bias,
                 const float* __restrict__ g, const float* __restrict__ beta,
                 const u16* __restrict__ resh, const u16* __restrict__ resl,
                 int ldRes, void* __restrict__ Y0, void* __restrict__ Y1, int ldY)
{
    __shared__ u16 Wb[32768];
    gemm_body<IN, LN, RES, AF32, OMODE>(Xa, Xb, ldX, Whi, Wlo, bias, g,
                                        beta, resh, resl, ldRes, Y0, Y1,
                                        ldY, Wb);
}

// qkv projections: grid.y = wsel in {0,1,2}; all plain-bf16 token-major out.
__global__ __launch_bounds__(256)
void qkv_proj(const u16* __restrict__ ph, const u16* __restrict__ pl,
              const u16* __restrict__ cwL, const float* __restrict__ cb,
              u16* __restrict__ qb, u16* __restrict__ kb, u16* __restrict__ vh)
{
    __shared__ u16 Wb[32768];
    int wsel = blockIdx.y;
    const u16* whi = cwL + (long)wsel * 65536;
    const u16* wlo = cwL + 393216 + (long)wsel * 65536;
    u16* Y = (wsel == 0) ? qb : (wsel == 1) ? kb : vh;
    gemm_body<256, false, false, false, 2>(
        ph, pl, 256, whi, wlo, cb + wsel * 256, nullptr, nullptr,
        nullptr, nullptr, 0, Y, nullptr, 256, Wb);
}

// ----------------------------------------------- combined in_proj @ qkv_proj
__global__ __launch_bounds__(256)
void combine_kernel(const float* __restrict__ inw, const float* __restrict__ inb,
                    const float* __restrict__ qw, const float* __restrict__ kw,
                    const float* __restrict__ vw, const float* __restrict__ qb,
                    const float* __restrict__ kb, const float* __restrict__ vb,
                    u16* __restrict__ cw, float* __restrict__ cb)
{
    int idx = blockIdx.y, L = idx / 3, wsel = idx % 3;
    const float* Wa = inw + (long)L * 768 * 256 + wsel * 65536;
    const float* ba = inb + L * 768 + wsel * 256;
    const float* Wf = (wsel == 0 ? qw : wsel == 1 ? kw : vw) + (long)L * 65536;
    const float* bf = (wsel == 0 ? qb : wsel == 1 ? kb : vb) + L * 256;

    int o = blockIdx.x, j = threadIdx.x;
    float s = 0.f;
    for (int mm = 0; mm < 256; ++mm)
        s += Wa[o * 256 + mm] * Wf[mm * 256 + j];
    u16 hb = f2b(s);
    cw[(long)idx * 65536 + o * 256 + j] = hb;
    cw[393216 + (long)idx * 65536 + o * 256 + j] = f2b(s - b2f(hb));

    __shared__ float red[256];
    red[j] = Wa[o * 256 + j] * bf[j];
    __syncthreads();
    for (int st = 128; st > 0; st >>= 1) {
        if (j < st) red[j] += red[j + st];
        __syncthreads();
    }
    if (j == 0) cb[idx * 256 + o] = red[0] + ba[o];
}

// ------------------------------------------- fp32 -> hi/lo bf16 weight planes
__global__ __launch_bounds__(256)
void cast_split_multi(const float* s0, u16* d0, int n0,
                      const float* s1, u16* d1, int n1,
                      const float* s2, u16* d2, int n2,
                      const float* s3, u16* d3, int n3,
                      const float* s4, u16* d4, int n4,
                      const float* s5, u16* d5, int n5)
{
    const float* s; u16* d; int n;
    switch (blockIdx.y) {
        case 0: s = s0; d = d0; n = n0; break;
        case 1: s = s1; d = d1; n = n1; break;
        case 2: s = s2; d = d2; n = n2; break;
        case 3: s = s3; d = d3; n = n3; break;
        case 4: s = s4; d = d4; n = n4; break;
        default: s = s5; d = d5; n = n5; break;
    }
    int i = (blockIdx.x * 256 + threadIdx.x) * 4;
    if (i >= n) return;
    float4 v = *(const float4*)&s[i];
    ushort4 h, l;
    h.x = f2b(v.x); l.x = f2b(v.x - b2f(h.x));
    h.y = f2b(v.y); l.y = f2b(v.y - b2f(h.y));
    h.z = f2b(v.z); l.z = f2b(v.z - b2f(h.z));
    h.w = f2b(v.w); l.w = f2b(v.w - b2f(h.w));
    *(ushort4*)&d[i] = h;
    *(ushort4*)&d[n + i] = l;
}

// ------------------------------------------------------- MFMA flash attention
// grid (n=64, h=4, sq=4), 256 thr = 4 waves x 32 q-rows. No-max softmax
// (scores O(0.1), shift-invariant). P and V single-plane bf16 (R8-validated:
// rounding errors average over the 512-token PV sum). V staged token-major ->
// LDS transpose (dense global reads; conflicts ~3M acceptable).
#define VTS 66
#define PS  68
#define EXP2SCALE 0.18033688089184986f   // 0.125 * log2(e)

__global__ __launch_bounds__(256)
void attn_kernel(const u16* __restrict__ qbuf, const u16* __restrict__ kbuf,
                 const u16* __restrict__ vh,
                 u16* __restrict__ ofh, u16* __restrict__ ofl)
{
    const int n = blockIdx.x, h = blockIdx.y, sq = blockIdx.z;
    const int tid = threadIdx.x;
    const int wv = tid >> 6, lane = tid & 63;
    const int quad = lane >> 4, l16 = lane & 15;

    __shared__ u16 Vth[64 * VTS];
    __shared__ u16 Pbh[4][32 * PS];

    bf16x8 qf[2][2];
    #pragma unroll
    for (int rt = 0; rt < 2; ++rt)
        #pragma unroll
        for (int kc = 0; kc < 2; ++kc) {
            long s = sq * 128 + wv * 32 + rt * 16 + l16;
            qf[rt][kc] = *(const bf16x8*)&qbuf[(s * 64 + n) * 256 + h * 64
                                               + kc * 32 + quad * 8];
        }

    f32x4 o[2][4];
    #pragma unroll
    for (int rt = 0; rt < 2; ++rt)
        #pragma unroll
        for (int dt = 0; dt < 4; ++dt) o[rt][dt] = f32x4{0.f, 0.f, 0.f, 0.f};
    float l_run[2][4] = {{0.f, 0.f, 0.f, 0.f}, {0.f, 0.f, 0.f, 0.f}};

    for (int tb = 0; tb < 8; ++tb) {
        // ---- stage V tile (hi only) transposed into LDS
        __syncthreads();
        for (int i = tid; i < 512; i += 256) {      // 64 t-rows x 8 col-chunks
            int t = i >> 3, c = i & 7;
            u16x8 hvv = *(const u16x8*)&vh[((long)(tb * 64 + t) * 64 + n) * 256
                                           + h * 64 + c * 8];
            #pragma unroll
            for (int j = 0; j < 8; ++j)
                Vth[(c * 8 + j) * VTS + t] = hvv[j];
        }
        __syncthreads();

        // ---- scores S = Q K^T
        f32x4 sA[2][4];
        #pragma unroll
        for (int rt = 0; rt < 2; ++rt)
            #pragma unroll
            for (int tt = 0; tt < 4; ++tt) sA[rt][tt] = f32x4{0.f, 0.f, 0.f, 0.f};
        #pragma unroll
        for (int kc = 0; kc < 2; ++kc)
            #pragma unroll
            for (int tt = 0; tt < 4; ++tt) {
                bf16x8 kf = *(const bf16x8*)
                    &kbuf[((long)(tb * 64 + tt * 16 + l16) * 64 + n) * 256
                          + h * 64 + kc * 32 + quad * 8];
                sA[0][tt] = __builtin_amdgcn_mfma_f32_16x16x32_bf16(
                    qf[0][kc], kf, sA[0][tt], 0, 0, 0);
                sA[1][tt] = __builtin_amdgcn_mfma_f32_16x16x32_bf16(
                    qf[1][kc], kf, sA[1][tt], 0, 0, 0);
            }

        // ---- softmax numerators (no max shift): p = exp2(s*0.125*log2e)
        #pragma unroll
        for (int rt = 0; rt < 2; ++rt)
            #pragma unroll
            for (int r = 0; r < 4; ++r) {
                float p0 = exp2f(sA[rt][0][r] * EXP2SCALE);
                float p1 = exp2f(sA[rt][1][r] * EXP2SCALE);
                float p2 = exp2f(sA[rt][2][r] * EXP2SCALE);
                float p3 = exp2f(sA[rt][3][r] * EXP2SCALE);
                int prow = (rt * 16 + quad * 4 + r) * PS + l16;
                Pbh[wv][prow +  0] = f2b(p0);
                Pbh[wv][prow + 16] = f2b(p1);
                Pbh[wv][prow + 32] = f2b(p2);
                Pbh[wv][prow + 48] = f2b(p3);
                l_run[rt][r] += (p0 + p1) + (p2 + p3);
            }

        // ---- O += P V  (single-plane)
        #pragma unroll
        for (int kc = 0; kc < 2; ++kc) {
            bf16x8 pfh[2];
            #pragma unroll
            for (int rt = 0; rt < 2; ++rt)
                pfh[rt] = ld2x64(&Pbh[wv][(rt * 16 + l16) * PS
                                          + kc * 32 + quad * 8]);
            #pragma unroll
            for (int dt = 0; dt < 4; ++dt) {
                bf16x8 vfh = ld4x32(&Vth[(dt * 16 + l16) * VTS
                                         + kc * 32 + quad * 8]);
                o[0][dt] = __builtin_amdgcn_mfma_f32_16x16x32_bf16(
                    pfh[0], vfh, o[0][dt], 0, 0, 0);
                o[1][dt] = __builtin_amdgcn_mfma_f32_16x16x32_bf16(
                    pfh[1], vfh, o[1][dt], 0, 0, 0);
            }
        }
    }

    // final l reduce across the 16 t-lanes
    #pragma unroll
    for (int off = 1; off < 16; off <<= 1)
        #pragma unroll
        for (int rt = 0; rt < 2; ++rt)
            #pragma unroll
            for (int r = 0; r < 4; ++r)
                l_run[rt][r] += __shfl_xor(l_run[rt][r], off, 64);

    #pragma unroll
    for (int rt = 0; rt < 2; ++rt)
        #pragma unroll
        for (int r = 0; r < 4; ++r) {
            float inv = 1.0f / l_run[rt][r];
            long s = sq * 128 + wv * 32 + rt * 16 + quad * 4 + r;
            #pragma unroll
            for (int dt = 0; dt < 4; ++dt) {
                long idx = (s * 64 + n) * 256 + h * 64 + dt * 16 + l16;
                float val = o[rt][dt][r] * inv;
                u16 hb = f2b(val);
                ofh[idx] = hb;
                ofl[idx] = f2b(val - b2f(hb));
            }
        }
}

// -------------------------------------------------- masked team segment-sum
__global__ __launch_bounds__(256)
void team_reduce_kernel(const float* __restrict__ x, const u16* __restrict__ ph,
                        const u16* __restrict__ pl, float* __restrict__ teams)
{
    int b = blockIdx.x, d = threadIdx.x;
    float acc = 0.f;
    for (int pp = 0; pp < 64; ++pp) {
        float flag = x[((long)b * 64 + pp) * 64 + 63];
        if (flag == 1.0f) {
            long idx = ((long)b * 64 + pp) * 256 + d;
            acc += b2f(ph[idx]) + b2f(pl[idx]);
        }
    }
    teams[(long)b * 512 + d]       = acc;
    teams[(long)b * 512 + 256 + d] = acc;
}

// ---------------------------------------- tail GEMM (512-row team layers)
template<int IN, int OUT, bool RES>
__global__ __launch_bounds__(256)
void tail_gemm(const float* __restrict__ X,
               const u16* __restrict__ Whi, const u16* __restrict__ Wlo,
               const float* __restrict__ bias,
               const float* __restrict__ g, const float* __restrict__ beta,
               const float* __restrict__ res, float* __restrict__ Y)
{
    constexpr int NTW = OUT / 64;
    constexpr int KT  = IN / 32;
    const int tid = threadIdx.x;
    const int wv = tid >> 6, lane = tid & 63;
    const int quad = lane >> 4, l16 = lane & 15;
    const int row0 = blockIdx.x * 16;
    const int colbase = wv * (OUT / 4);

    f32x4 acc[NTW];
    #pragma unroll
    for (int nt = 0; nt < NTW; ++nt) acc[nt] = f32x4{0.f, 0.f, 0.f, 0.f};

    #pragma unroll
    for (int kt = 0; kt < KT; ++kt) {
        float av[8];
        long aofs = (long)(row0 + l16) * IN + kt * 32 + quad * 8;
        *(f32x4*)&av[0] = *(const f32x4*)&X[aofs];
        *(f32x4*)&av[4] = *(const f32x4*)&X[aofs + 4];
        bf16x8 ah, al;
        split8(av, ah, al);
        #pragma unroll
        for (int nt = 0; nt < NTW; ++nt) {
            long wofs = (long)(colbase + nt * 16 + l16) * IN + kt * 32 + quad * 8;
            bf16x8 bhi = *(const bf16x8*)&Whi[wofs];
            bf16x8 blo = *(const bf16x8*)&Wlo[wofs];
            acc[nt] = __builtin_amdgcn_mfma_f32_16x16x32_bf16(al, bhi, acc[nt], 0, 0, 0);
            acc[nt] = __builtin_amdgcn_mfma_f32_16x16x32_bf16(ah, blo, acc[nt], 0, 0, 0);
            acc[nt] = __builtin_amdgcn_mfma_f32_16x16x32_bf16(ah, bhi, acc[nt], 0, 0, 0);
        }
    }

    #pragma unroll
    for (int nt = 0; nt < NTW; ++nt) {
        float bc = bias[colbase + nt * 16 + l16];
        #pragma unroll
        for (int r = 0; r < 4; ++r) acc[nt][r] += bc;
    }

    float s1[4] = {0, 0, 0, 0}, s2[4] = {0, 0, 0, 0};
    #pragma unroll
    for (int nt = 0; nt < NTW; ++nt)
        #pragma unroll
        for (int r = 0; r < 4; ++r) {
            s1[r] += acc[nt][r];
            s2[r] += acc[nt][r] * acc[nt][r];
        }
    #pragma unroll
    for (int off = 1; off < 16; off <<= 1)
        #pragma unroll
        for (int r = 0; r < 4; ++r) {
            s1[r] += __shfl_xor(s1[r], off, 64);
            s2[r] += __shfl_xor(s2[r], off, 64);
        }
    __shared__ float r1[64], r2[64];
    if (l16 == 0) {
        #pragma unroll
        for (int r = 0; r < 4; ++r) {
            r1[wv * 16 + quad * 4 + r] = s1[r];
            r2[wv * 16 + quad * 4 + r] = s2[r];
        }
    }
    __syncthreads();
    float mean[4], rstd[4];
    #pragma unroll
    for (int r = 0; r < 4; ++r) {
        int rr = quad * 4 + r;
        float t1 = r1[rr] + r1[16 + rr] + r1[32 + rr] + r1[48 + rr];
        float t2 = r2[rr] + r2[16 + rr] + r2[32 + rr] + r2[48 + rr];
        mean[r] = t1 * (1.0f / OUT);
        float var = t2 * (1.0f / OUT) - mean[r] * mean[r];
        rstd[r] = rsqrtf(var + 1e-5f);
    }
    #pragma unroll
    for (int nt = 0; nt < NTW; ++nt) {
        int col = colbase + nt * 16 + l16;
        float gc = g[col], bc2 = beta[col];
        #pragma unroll
        for (int r = 0; r < 4; ++r) {
            int row = row0 + quad * 4 + r;
            float v = (acc[nt][r] - mean[r]) * rstd[r] * gc + bc2;
            if constexpr (RES) v += res[(long)row * OUT + col];
            Y[(long)row * OUT + col] = v;
        }
    }
}

// -------------------------------------------------------- standalone LN (lnf)
__global__ __launch_bounds__(64)
void ln_kernel(const float* __restrict__ X, const float* __restrict__ g,
               const float* __restrict__ b, float* __restrict__ Y)
{
    int row = blockIdx.x, lane = threadIdx.x;
    float4 v = *(const float4*)&X[(long)row * 256 + lane * 4];
    float s1 = v.x + v.y + v.z + v.w;
    float s2 = v.x*v.x + v.y*v.y + v.z*v.z + v.w*v.w;
    #pragma unroll
    for (int off = 32; off > 0; off >>= 1) {
        s1 += __shfl_xor(s1, off, 64);
        s2 += __shfl_xor(s2, off, 64);
    }
    float mean = s1 * (1.f / 256.f);
    float rstd = rsqrtf(s2 * (1.f / 256.f) - mean * mean + 1e-5f);
    float4 gg = *(const float4*)&g[lane * 4];
    float4 bb = *(const float4*)&b[lane * 4];
    float4 o;
    o.x = (v.x - mean) * rstd * gg.x + bb.x;
    o.y = (v.y - mean) * rstd * gg.y + bb.y;
    o.z = (v.z - mean) * rstd * gg.z + bb.z;
    o.w = (v.w - mean) * rstd * gg.w + bb.w;
    *(float4*)&Y[(long)row * 256 + lane * 4] = o;
}

// ------------------------------------------------------------- final predict
__global__ __launch_bounds__(64)
void pred_kernel(const float* __restrict__ X, const float* __restrict__ pw,
                 const float* __restrict__ pb, float* __restrict__ out)
{
    int row = blockIdx.x, lane = threadIdx.x;
    float4 v = *(const float4*)&X[(long)row * 256 + lane * 4];
    float4 w = *(const float4*)&pw[lane * 4];
    float s = v.x*w.x + v.y*w.y + v.z*w.z + v.w*w.w;
    #pragma unroll
    for (int off = 32; off > 0; off >>= 1) s += __shfl_xor(s, off, 64);
    if (lane == 0) out[row] = s + pb[0];
}

// =========================================================================
extern "C" void kernel_launch(void* const* d_in, const int* in_sizes, int n_in,
                              void* d_out, int out_size, void* d_ws, size_t ws_size,
                              hipStream_t stream)
{
    const float* x         = (const float*)d_in[0];
    const float* emb_w     = (const float*)d_in[1];
    const float* emb_b     = (const float*)d_in[2];
    const float* emb_g     = (const float*)d_in[3];
    const float* emb_beta  = (const float*)d_in[4];
    const float* post_w    = (const float*)d_in[5];
    const float* post_b    = (const float*)d_in[6];
    const float* post_g    = (const float*)d_in[7];
    const float* post_beta = (const float*)d_in[8];
    const float* attn_qw   = (const float*)d_in[9];
    const float* attn_qb   = (const float*)d_in[10];
    const float* attn_kw   = (const float*)d_in[11];
    const float* attn_kb   = (const float*)d_in[12];
    const float* attn_vw   = (const float*)d_in[13];
    const float* attn_vb   = (const float*)d_in[14];
    const float* attn_inw  = (const float*)d_in[15];
    const float* attn_inb  = (const float*)d_in[16];
    const float* attn_outw = (const float*)d_in[17];
    const float* attn_outb = (const float*)d_in[18];
    const float* attn_g    = (const float*)d_in[19];
    const float* attn_beta = (const float*)d_in[20];
    const float* player_w  = (const float*)d_in[21];
    const float* player_b  = (const float*)d_in[22];
    const float* player_g  = (const float*)d_in[23];
    const float* player_bt = (const float*)d_in[24];
    const float* team_w    = (const float*)d_in[25];
    const float* team_b    = (const float*)d_in[26];
    const float* team_g    = (const float*)d_in[27];
    const float* team_beta = (const float*)d_in[28];
    const float* pre_w     = (const float*)d_in[29];
    const float* pre_b     = (const float*)d_in[30];
    const float* pre_g     = (const float*)d_in[31];
    const float* pre_beta  = (const float*)d_in[32];
    const float* lnf_g     = (const float*)d_in[33];
    const float* lnf_b     = (const float*)d_in[34];
    const float* pred_w    = (const float*)d_in[35];
    const float* pred_b    = (const float*)d_in[36];

    // ---- workspace layout
    char* base = (char*)d_ws;
    const size_t NR = (size_t)32768 * 256;
    u16* ph  = (u16*)base;  base += NR * 2;
    u16* pl  = (u16*)base;  base += NR * 2;
    u16* ofh = (u16*)base;  base += NR * 2;
    u16* ofl = (u16*)base;  base += NR * 2;
    u16* vh  = (u16*)base;  base += NR * 2;
    u16* qb  = (u16*)base;  base += NR * 2;
    u16* kb  = (u16*)base;  base += NR * 2;
    float* teams0 = (float*)base; base += (size_t)512 * 512 * 4;
    float* teams1 = (float*)base; base += (size_t)512 * 512 * 4;
    float* o5     = (float*)base; base += (size_t)512 * 256 * 4;
    u16* emb_wp    = (u16*)base;  base += (size_t)2 * 16384 * 2;
    u16* post_wp   = (u16*)base;  base += (size_t)2 * 65536 * 2;
    u16* outw_p    = (u16*)base;  base += (size_t)2 * 131072 * 2;
    u16* player_wp = (u16*)base;  base += (size_t)2 * 131072 * 2;
    u16* team_wp   = (u16*)base;  base += (size_t)2 * 524288 * 2;
    u16* pre_wp    = (u16*)base;  base += (size_t)2 * 131072 * 2;
    u16* cwb       = (u16*)base;  base += (size_t)2 * 393216 * 2;
    float* cbf     = (float*)base; base += (size_t)1536 * 4;

    // 1) weights -> hi/lo bf16 planes
    cast_split_multi<<<dim3(512, 6), 256, 0, stream>>>(
        emb_w, emb_wp, 16384,
        post_w, post_wp, 65536,
        attn_outw, outw_p, 131072,
        player_w, player_wp, 131072,
        team_w, team_wp, 524288,
        pre_w, pre_wp, 131072);

    // 2) combined qkv weights
    combine_kernel<<<dim3(256, 6), 256, 0, stream>>>(
        attn_inw, attn_inb, attn_qw, attn_kw, attn_vw,
        attn_qb, attn_kb, attn_vb, cwb, cbf);

    // 3) embedding + post-embedding
    gemm_kernel<64, true, false, true, 1><<<512, 256, 0, stream>>>(
        x, nullptr, 64, emb_wp, emb_wp + 16384, emb_b, emb_g, emb_beta,
        nullptr, nullptr, 0, ph, pl, 256);
    gemm_kernel<256, true, true, false, 1><<<512, 256, 0, stream>>>(
        ph, pl, 256, post_wp, post_wp + 65536, post_b, post_g, post_beta,
        ph, pl, 256, ph, pl, 256);

    // 4) attention layers
    for (int L = 0; L < 2; ++L) {
        qkv_proj<<<dim3(512, 3), 256, 0, stream>>>(
            ph, pl, cwb + (size_t)L * 3 * 65536, cbf + L * 768, qb, kb, vh);
        attn_kernel<<<dim3(64, 4, 4), 256, 0, stream>>>(qb, kb, vh, ofh, ofl);
        gemm_kernel<256, true, true, false, 1><<<512, 256, 0, stream>>>(
            ofh, ofl, 256, outw_p + (size_t)L * 65536,
            outw_p + 131072 + (size_t)L * 65536, attn_outb + L * 256,
            attn_g + L * 256, attn_beta + L * 256, ph, pl, 256, ph, pl, 256);
    }

    // 5) player layers
    for (int L = 0; L < 2; ++L)
        gemm_kernel<256, true, true, false, 1><<<512, 256, 0, stream>>>(
            ph, pl, 256, player_wp + (size_t)L * 65536,
            player_wp + 131072 + (size_t)L * 65536, player_b + L * 256,
            player_g + L * 256, player_bt + L * 256, ph, pl, 256, ph, pl, 256);

    // 6) masked segment-sum -> teams0 fp32 [512][512]
    team_reduce_kernel<<<512, 256, 0, stream>>>(x, ph, pl, teams0);

    // 7) team layers (ping-pong)
    tail_gemm<512, 512, true><<<32, 256, 0, stream>>>(
        teams0, team_wp, team_wp + 524288, team_b,
        team_g, team_beta, teams0, teams1);
    tail_gemm<512, 512, true><<<32, 256, 0, stream>>>(
        teams1, team_wp + 262144, team_wp + 524288 + 262144, team_b + 512,
        team_g + 512, team_beta + 512, teams1, teams0);

    // 8) pre (512->256) + lnf + pred
    tail_gemm<512, 256, false><<<32, 256, 0, stream>>>(
        teams0, pre_wp, pre_wp + 131072, pre_b, pre_g, pre_beta,
        nullptr, o5);
    ln_kernel<<<512, 64, 0, stream>>>(o5, lnf_g, lnf_b, o5);
    pred_kernel<<<512, 64, 0, stream>>>(o5, pred_w, pred_b, (float*)d_out);
}